// Round 1
// baseline (22392.451 us; speedup 1.0000x reference)
//
#include <hip/hip_runtime.h>

typedef __attribute__((ext_vector_type(4))) float f32x4;
typedef __attribute__((ext_vector_type(8))) short short8;

#define SEQn 2048
#define HIDn 1024
#define G4n  4096
#define VOCABn 32000

static __device__ __forceinline__ unsigned short f2bf(float f) {
  unsigned u = __float_as_uint(f);
  u += 0x7fffu + ((u >> 16) & 1u);   // round-to-nearest-even
  return (unsigned short)(u >> 16);
}

// ---------------------------------------------------------------------------
// K1: xW = gather(emb_table, idx) @ W_ih^T + (b_ih + b_hh)   [2048 x 4096] f32
// 64x64 tile, BK=32, 256 threads, 4x4 micro-tile per thread.
// ---------------------------------------------------------------------------
__global__ __launch_bounds__(256) void embed_xw(
    const int* __restrict__ idx, const float* __restrict__ emb,
    const float* __restrict__ Wih, const float* __restrict__ bih,
    const float* __restrict__ bhh, float* __restrict__ xW)
{
  __shared__ float As[64][33];
  __shared__ float Bs[64][33];
  const int tid = threadIdx.x;
  const int n0 = blockIdx.x * 64;
  const int m0 = blockIdx.y * 64;
  const int lr = tid >> 2, lq = tid & 3;
  const int tx = tid & 15, ty = tid >> 4;
  const size_t arow = (size_t)idx[m0 + lr] * 1024 + lq * 8;
  const size_t brow = (size_t)(n0 + lr) * 1024 + lq * 8;
  float bi[4];
#pragma unroll
  for (int j = 0; j < 4; ++j)
    bi[j] = bih[n0 + tx * 4 + j] + bhh[n0 + tx * 4 + j];
  float acc[4][4] = {};
  for (int kt = 0; kt < 32; ++kt) {
    float4 a0 = *(const float4*)(emb + arow + kt * 32);
    float4 a1 = *(const float4*)(emb + arow + kt * 32 + 4);
    float4 b0 = *(const float4*)(Wih + brow + kt * 32);
    float4 b1 = *(const float4*)(Wih + brow + kt * 32 + 4);
    __syncthreads();
    float* ad = &As[lr][lq * 8];
    ad[0]=a0.x; ad[1]=a0.y; ad[2]=a0.z; ad[3]=a0.w;
    ad[4]=a1.x; ad[5]=a1.y; ad[6]=a1.z; ad[7]=a1.w;
    float* bd = &Bs[lr][lq * 8];
    bd[0]=b0.x; bd[1]=b0.y; bd[2]=b0.z; bd[3]=b0.w;
    bd[4]=b1.x; bd[5]=b1.y; bd[6]=b1.z; bd[7]=b1.w;
    __syncthreads();
#pragma unroll 8
    for (int kk = 0; kk < 32; ++kk) {
      float a[4], b[4];
#pragma unroll
      for (int i = 0; i < 4; ++i) a[i] = As[ty * 4 + i][kk];
#pragma unroll
      for (int j = 0; j < 4; ++j) b[j] = Bs[tx * 4 + j][kk];
#pragma unroll
      for (int i = 0; i < 4; ++i)
#pragma unroll
        for (int j = 0; j < 4; ++j)
          acc[i][j] = fmaf(a[i], b[j], acc[i][j]);
    }
  }
#pragma unroll
  for (int i = 0; i < 4; ++i) {
    float4 v = {acc[i][0] + bi[0], acc[i][1] + bi[1],
                acc[i][2] + bi[2], acc[i][3] + bi[3]};
    *(float4*)(xW + (size_t)(m0 + ty * 4 + i) * G4n + n0 + tx * 4) = v;
  }
}

// ---------------------------------------------------------------------------
// K2: persistent LSTM scan. 256 WGs x 256 threads. Each WG owns 4 hidden
// units (16 W_hh rows, LDS-resident). h exchanged via global (agent-scope
// atomics) with a two-level monotonic spin barrier.
// ---------------------------------------------------------------------------
__global__ __launch_bounds__(256, 1) void lstm_scan(
    const float* __restrict__ xW, const float* __restrict__ Whh,
    float* hb0, float* hb1, unsigned* bar,
    unsigned short* __restrict__ hsbf,
    float* __restrict__ outHT, float* __restrict__ outCT)
{
  extern __shared__ float smem[];
  float* wsm = smem;                // [16][1028] padded
  float* hsm = smem + 16 * 1028;    // [1024]
  float* red = hsm + 1024;          // [16]
  const int tid = threadIdx.x;
  const int wg = blockIdx.x;        // 0..255
  const int u0 = wg * 4;
  // preload the 16 W_hh rows this WG needs (row rl = g*4+j <-> g*1024+u0+j)
#pragma unroll
  for (int rl = 0; rl < 16; ++rl) {
    int g = rl >> 2, j = rl & 3;
    float4 v = *(const float4*)(Whh + (size_t)(g * 1024 + u0 + j) * 1024 + tid * 4);
    *(float4*)(wsm + rl * 1028 + tid * 4) = v;
  }
  const int rl = tid >> 4;
  const int l16 = tid & 15;
  const float* wrow = wsm + rl * 1028;
  float c_reg = 0.f;
  __syncthreads();
  for (int t = 0; t < 2048; ++t) {
    // prefetch this step's xW entries (independent of h -> hides latency)
    float xg0, xg1, xg2, xg3;
    if (tid < 4) {
      const float* xr = xW + (size_t)t * G4n + u0 + tid;
      xg0 = xr[0]; xg1 = xr[1024]; xg2 = xr[2048]; xg3 = xr[3072];
    }
    // load h(t) into LDS (coherent loads: written by other XCDs)
    const float* hsrc = (t & 1) ? hb1 : hb0;
#pragma unroll
    for (int c = 0; c < 4; ++c)
      hsm[tid + 256 * c] = __hip_atomic_load(hsrc + tid + 256 * c,
                                             __ATOMIC_RELAXED, __HIP_MEMORY_SCOPE_AGENT);
    __syncthreads();
    // dot: row rl over its 64-element slice (lane16-interleaved float4s)
    float acc = 0.f;
#pragma unroll
    for (int k = 0; k < 16; ++k) {
      const int e = l16 * 4 + k * 64;
      float4 wv = *(const float4*)(wrow + e);
      float4 hv = *(const float4*)(hsm + e);
      acc = fmaf(wv.x, hv.x, acc);
      acc = fmaf(wv.y, hv.y, acc);
      acc = fmaf(wv.z, hv.z, acc);
      acc = fmaf(wv.w, hv.w, acc);
    }
    acc += __shfl_xor(acc, 8);
    acc += __shfl_xor(acc, 4);
    acc += __shfl_xor(acc, 2);
    acc += __shfl_xor(acc, 1);
    if (l16 == 0) red[rl] = acc;
    __syncthreads();
    if (tid < 4) {
      const int j = tid;
      float gi = xg0 + red[j];
      float gf = xg1 + red[4 + j];
      float gg = xg2 + red[8 + j];
      float go = xg3 + red[12 + j];
      float si = 1.f / (1.f + __expf(-gi));
      float sf = 1.f / (1.f + __expf(-gf));
      float tg = tanhf(gg);
      float so = 1.f / (1.f + __expf(-go));
      c_reg = fmaf(sf, c_reg, si * tg);
      float h = so * tanhf(c_reg);
      float* hdst = (t & 1) ? hb0 : hb1;
      __hip_atomic_store(hdst + u0 + j, h, __ATOMIC_RELAXED, __HIP_MEMORY_SCOPE_AGENT);
      hsbf[(size_t)t * 1024 + u0 + j] = f2bf(h);
      if (t == 2047) { outHT[u0 + j] = h; outCT[u0 + j] = c_reg; }
    }
    __syncthreads();  // h stores drained (waitcnt before s_barrier) before signal
    if (tid == 0) {
      unsigned* xc = bar + (wg & 7) * 256;   // 8 group counters, 1KB apart
      unsigned* gc = bar + 2048;             // global counter
      unsigned a = __hip_atomic_fetch_add(xc, 1u, __ATOMIC_RELEASE, __HIP_MEMORY_SCOPE_AGENT);
      if (a == 32u * (t + 1) - 1u)           // last of 32 in group this step
        __hip_atomic_fetch_add(gc, 1u, __ATOMIC_RELEASE, __HIP_MEMORY_SCOPE_AGENT);
      while (__hip_atomic_load(gc, __ATOMIC_ACQUIRE, __HIP_MEMORY_SCOPE_AGENT) < 8u * (t + 1))
        __builtin_amdgcn_s_sleep(1);
    }
    __syncthreads();
  }
}

// ---------------------------------------------------------------------------
// K3: logits = relu(hs_bf16 @ W_lin^T + b_lin) -> d_out [2048 x 32000] f32
// 128x128 tile, BK=32, 4 waves (2x2), mfma_f32_16x16x32_bf16.
// W_lin converted f32->bf16 on the fly during B staging.
// ---------------------------------------------------------------------------
__global__ __launch_bounds__(256) void gemm_logits(
    const unsigned short* __restrict__ hs, const float* __restrict__ Wlin,
    const float* __restrict__ blin, float* __restrict__ out)
{
  __shared__ unsigned short As[128][32];
  __shared__ unsigned short Bs[128][32];
  const int tid = threadIdx.x;
  const int n0 = blockIdx.x * 128;
  const int m0 = blockIdx.y * 128;
  const int r2 = tid >> 1, half = tid & 1;
  const int lane = tid & 63;
  const int wv = tid >> 6;
  const int wm = (wv >> 1) * 64;
  const int wn = (wv & 1) * 64;
  const int fr = lane & 15;
  const int fq = lane >> 4;
  f32x4 acc[4][4];
#pragma unroll
  for (int i = 0; i < 4; ++i)
#pragma unroll
    for (int j = 0; j < 4; ++j)
      acc[i][j] = (f32x4){0.f, 0.f, 0.f, 0.f};
  for (int kt = 0; kt < 32; ++kt) {
    const size_t ak = (size_t)(m0 + r2) * 1024 + kt * 32 + half * 16;
    int4 aA = *(const int4*)(hs + ak);
    int4 aB = *(const int4*)(hs + ak + 8);
    const size_t bk = (size_t)(n0 + r2) * 1024 + kt * 32 + half * 16;
    float4 b0 = *(const float4*)(Wlin + bk);
    float4 b1 = *(const float4*)(Wlin + bk + 4);
    float4 b2 = *(const float4*)(Wlin + bk + 8);
    float4 b3 = *(const float4*)(Wlin + bk + 12);
    __syncthreads();
    *(int4*)&As[r2][half * 16] = aA;
    *(int4*)&As[r2][half * 16 + 8] = aB;
    union { unsigned short u[8]; int4 v; } p0, p1;
    p0.u[0]=f2bf(b0.x); p0.u[1]=f2bf(b0.y); p0.u[2]=f2bf(b0.z); p0.u[3]=f2bf(b0.w);
    p0.u[4]=f2bf(b1.x); p0.u[5]=f2bf(b1.y); p0.u[6]=f2bf(b1.z); p0.u[7]=f2bf(b1.w);
    p1.u[0]=f2bf(b2.x); p1.u[1]=f2bf(b2.y); p1.u[2]=f2bf(b2.z); p1.u[3]=f2bf(b2.w);
    p1.u[4]=f2bf(b3.x); p1.u[5]=f2bf(b3.y); p1.u[6]=f2bf(b3.z); p1.u[7]=f2bf(b3.w);
    *(int4*)&Bs[r2][half * 16] = p0.v;
    *(int4*)&Bs[r2][half * 16 + 8] = p1.v;
    __syncthreads();
    short8 af[4], bfv[4];
#pragma unroll
    for (int i = 0; i < 4; ++i) af[i] = *(const short8*)&As[wm + i * 16 + fr][fq * 8];
#pragma unroll
    for (int j = 0; j < 4; ++j) bfv[j] = *(const short8*)&Bs[wn + j * 16 + fr][fq * 8];
#pragma unroll
    for (int i = 0; i < 4; ++i)
#pragma unroll
      for (int j = 0; j < 4; ++j)
        acc[i][j] = __builtin_amdgcn_mfma_f32_16x16x32_bf16(af[i], bfv[j], acc[i][j], 0, 0, 0);
  }
#pragma unroll
  for (int j = 0; j < 4; ++j) {
    const int col = n0 + wn + j * 16 + fr;
    const float bias = blin[col];
#pragma unroll
    for (int i = 0; i < 4; ++i) {
#pragma unroll
      for (int r = 0; r < 4; ++r) {
        const int row = m0 + wm + i * 16 + fq * 4 + r;
        float v = acc[i][j][r] + bias;
        out[(size_t)row * VOCABn + col] = fmaxf(v, 0.f);
      }
    }
  }
}

// ---------------------------------------------------------------------------
// K4: in-place log_softmax per row of d_out (2048 rows x 32000).
// ---------------------------------------------------------------------------
__global__ __launch_bounds__(256) void logsoftmax_rows(float* __restrict__ out)
{
  __shared__ float sred[4];
  __shared__ float ssum[4];
  const int tid = threadIdx.x;
  float* p = out + (size_t)blockIdx.x * VOCABn;
  float m = -1e30f;
  for (int i = tid; i < VOCABn / 4; i += 256) {
    float4 v = ((const float4*)p)[i];
    m = fmaxf(m, fmaxf(fmaxf(v.x, v.y), fmaxf(v.z, v.w)));
  }
#pragma unroll
  for (int s = 32; s >= 1; s >>= 1) m = fmaxf(m, __shfl_xor(m, s));
  if ((tid & 63) == 0) sred[tid >> 6] = m;
  __syncthreads();
  m = fmaxf(fmaxf(sred[0], sred[1]), fmaxf(sred[2], sred[3]));
  float s = 0.f;
  for (int i = tid; i < VOCABn / 4; i += 256) {
    float4 v = ((const float4*)p)[i];
    s += __expf(v.x - m) + __expf(v.y - m) + __expf(v.z - m) + __expf(v.w - m);
  }
#pragma unroll
  for (int sh = 32; sh >= 1; sh >>= 1) s += __shfl_xor(s, sh);
  if ((tid & 63) == 0) ssum[tid >> 6] = s;
  __syncthreads();
  s = ssum[0] + ssum[1] + ssum[2] + ssum[3];
  const float lse = m + logf(s);
  for (int i = tid; i < VOCABn / 4; i += 256) {
    float4 v = ((const float4*)p)[i];
    v.x -= lse; v.y -= lse; v.z -= lse; v.w -= lse;
    ((float4*)p)[i] = v;
  }
}

// ---------------------------------------------------------------------------
extern "C" void kernel_launch(void* const* d_in, const int* in_sizes, int n_in,
                              void* d_out, int out_size, void* d_ws, size_t ws_size,
                              hipStream_t stream) {
  const int*   input_x = (const int*)d_in[0];
  const float* emb     = (const float*)d_in[1];
  const float* Wih     = (const float*)d_in[2];
  const float* Whh     = (const float*)d_in[3];
  const float* bih     = (const float*)d_in[4];
  const float* bhh     = (const float*)d_in[5];
  const float* Wlin    = (const float*)d_in[6];
  const float* blin    = (const float*)d_in[7];
  float* out = (float*)d_out;
  char* ws = (char*)d_ws;

  unsigned* bar = (unsigned*)ws;                     // [0, 16KB): barrier counters
  float* hb0 = (float*)(ws + 16384);                 // 4KB
  float* hb1 = (float*)(ws + 20480);                 // 4KB
  float* xW  = (float*)(ws + 131072);                // 32MB: [2048][4096] f32
  unsigned short* hsbf = (unsigned short*)(ws + 131072 + (size_t)SEQn * G4n * 4); // 4MB bf16
  float* outHT = out + (size_t)SEQn * VOCABn;
  float* outCT = outHT + 1024;

  hipMemsetAsync(d_ws, 0, 32768, stream);            // zero barrier counters + h0

  dim3 g1(64, 32);
  embed_xw<<<g1, 256, 0, stream>>>(input_x, emb, Wih, bih, bhh, xW);

  lstm_scan<<<256, 256, 69952, stream>>>(xW, Whh, hb0, hb1, bar, hsbf, outHT, outCT);

  dim3 g2(250, 16);
  gemm_logits<<<g2, 256, 0, stream>>>(hsbf, Wlin, blin, out);

  logsoftmax_rows<<<2048, 256, 0, stream>>>(out);
}

// Round 3
// 6465.546 us; speedup vs baseline: 3.4634x; 3.4634x over previous
//
#include <hip/hip_runtime.h>

typedef __attribute__((ext_vector_type(4))) float f32x4;
typedef __attribute__((ext_vector_type(8))) short short8;

#define SEQn 2048
#define HIDn 1024
#define G4n  4096
#define VOCABn 32000

static __device__ __forceinline__ unsigned short f2bf(float f) {
  unsigned u = __float_as_uint(f);
  u += 0x7fffu + ((u >> 16) & 1u);   // round-to-nearest-even
  return (unsigned short)(u >> 16);
}

static __device__ __forceinline__ float sigm_fast(float x) {
  return __builtin_amdgcn_rcpf(1.f + __expf(-x));
}
static __device__ __forceinline__ float tanh_fast(float x) {
  return 1.f - 2.f * __builtin_amdgcn_rcpf(1.f + __expf(2.f * x));
}

// ---------------------------------------------------------------------------
// K1: xW = gather(emb_table, idx) @ W_ih^T + (b_ih + b_hh)   [2048 x 4096] f32
// ---------------------------------------------------------------------------
__global__ __launch_bounds__(256) void embed_xw(
    const int* __restrict__ idx, const float* __restrict__ emb,
    const float* __restrict__ Wih, const float* __restrict__ bih,
    const float* __restrict__ bhh, float* __restrict__ xW)
{
  __shared__ float As[64][33];
  __shared__ float Bs[64][33];
  const int tid = threadIdx.x;
  const int n0 = blockIdx.x * 64;
  const int m0 = blockIdx.y * 64;
  const int lr = tid >> 2, lq = tid & 3;
  const int tx = tid & 15, ty = tid >> 4;
  const size_t arow = (size_t)idx[m0 + lr] * 1024 + lq * 8;
  const size_t brow = (size_t)(n0 + lr) * 1024 + lq * 8;
  float bi[4];
#pragma unroll
  for (int j = 0; j < 4; ++j)
    bi[j] = bih[n0 + tx * 4 + j] + bhh[n0 + tx * 4 + j];
  float acc[4][4] = {};
  for (int kt = 0; kt < 32; ++kt) {
    float4 a0 = *(const float4*)(emb + arow + kt * 32);
    float4 a1 = *(const float4*)(emb + arow + kt * 32 + 4);
    float4 b0 = *(const float4*)(Wih + brow + kt * 32);
    float4 b1 = *(const float4*)(Wih + brow + kt * 32 + 4);
    __syncthreads();
    float* ad = &As[lr][lq * 8];
    ad[0]=a0.x; ad[1]=a0.y; ad[2]=a0.z; ad[3]=a0.w;
    ad[4]=a1.x; ad[5]=a1.y; ad[6]=a1.z; ad[7]=a1.w;
    float* bd = &Bs[lr][lq * 8];
    bd[0]=b0.x; bd[1]=b0.y; bd[2]=b0.z; bd[3]=b0.w;
    bd[4]=b1.x; bd[5]=b1.y; bd[6]=b1.z; bd[7]=b1.w;
    __syncthreads();
#pragma unroll 8
    for (int kk = 0; kk < 32; ++kk) {
      float a[4], b[4];
#pragma unroll
      for (int i = 0; i < 4; ++i) a[i] = As[ty * 4 + i][kk];
#pragma unroll
      for (int j = 0; j < 4; ++j) b[j] = Bs[tx * 4 + j][kk];
#pragma unroll
      for (int i = 0; i < 4; ++i)
#pragma unroll
        for (int j = 0; j < 4; ++j)
          acc[i][j] = fmaf(a[i], b[j], acc[i][j]);
    }
  }
#pragma unroll
  for (int i = 0; i < 4; ++i) {
    float4 v = {acc[i][0] + bi[0], acc[i][1] + bi[1],
                acc[i][2] + bi[2], acc[i][3] + bi[3]};
    *(float4*)(xW + (size_t)(m0 + ty * 4 + i) * G4n + n0 + tx * 4) = v;
  }
}

// ---------------------------------------------------------------------------
// K2: persistent LSTM scan. 256 WGs x 256 threads, W_hh LDS-resident
// (stride 1032 floats -> 2-way LDS banking = free).
// Sync: each WG publishes its 4 h values as 8B packets (h_bits | tag<<32)
// via relaxed agent-scope 64b atomic stores, double-buffered by parity.
// Consumers poll the packets directly — tag travels WITH the data, so no
// fences / flag stores / extra round trips. Bounded spin budget (~0.5 s)
// guarantees kernel termination even if co-residency fails.
// ---------------------------------------------------------------------------
__global__ __launch_bounds__(256, 1) void lstm_scan(
    const float* __restrict__ xW, const float* __restrict__ Whh,
    unsigned long long* pk0, unsigned long long* pk1,
    unsigned short* __restrict__ hsbf,
    float* __restrict__ outHT, float* __restrict__ outCT)
{
  extern __shared__ float smem[];
  float* wsm = smem;                 // [16][1032] padded
  float* hsm = smem + 16 * 1032;     // [1024]
  float* red = hsm + 1024;           // [16]
  const int tid = threadIdx.x;
  const int wg = blockIdx.x;         // 0..255
  const int u0 = wg * 4;
#pragma unroll
  for (int rl = 0; rl < 16; ++rl) {
    int g = rl >> 2, j = rl & 3;
    float4 v = *(const float4*)(Whh + (size_t)(g * 1024 + u0 + j) * 1024 + tid * 4);
    *(float4*)(wsm + rl * 1032 + tid * 4) = v;
  }
  const int rl = tid >> 4;
  const int l16 = tid & 15;
  const float* wrow = wsm + rl * 1032;
  float c_reg = 0.f;
  int budget = 1 << 21;              // spin escape hatch (never fires if sound)
  // prefetch xW for t=0
  float xg0, xg1, xg2, xg3;
  if (tid < 4) {
    const float* xr = xW + u0 + tid;
    xg0 = xr[0]; xg1 = xr[1024]; xg2 = xr[2048]; xg3 = xr[3072];
  }
  __syncthreads();
  for (int t = 0; t < 2048; ++t) {
    // poll h(t) packets: buffer parity t&1, tag >= t  (t=0: memset gave tag 0)
    const unsigned long long* src = (t & 1) ? pk1 : pk0;
    unsigned long long q0, q1, q2, q3;
    for (;;) {
      q0 = __hip_atomic_load(src + tid,       __ATOMIC_RELAXED, __HIP_MEMORY_SCOPE_AGENT);
      q1 = __hip_atomic_load(src + tid + 256, __ATOMIC_RELAXED, __HIP_MEMORY_SCOPE_AGENT);
      q2 = __hip_atomic_load(src + tid + 512, __ATOMIC_RELAXED, __HIP_MEMORY_SCOPE_AGENT);
      q3 = __hip_atomic_load(src + tid + 768, __ATOMIC_RELAXED, __HIP_MEMORY_SCOPE_AGENT);
      unsigned m01 = min((unsigned)(q0 >> 32), (unsigned)(q1 >> 32));
      unsigned m23 = min((unsigned)(q2 >> 32), (unsigned)(q3 >> 32));
      if (min(m01, m23) >= (unsigned)t || budget <= 0) break;
      --budget;
      __builtin_amdgcn_s_sleep(1);
    }
    hsm[tid]       = __uint_as_float((unsigned)q0);
    hsm[tid + 256] = __uint_as_float((unsigned)q1);
    hsm[tid + 512] = __uint_as_float((unsigned)q2);
    hsm[tid + 768] = __uint_as_float((unsigned)q3);
    __syncthreads();                 // B1: hsm ready
    // dot: row rl over lane16-interleaved float4 slices
    float acc = 0.f;
#pragma unroll
    for (int k = 0; k < 16; ++k) {
      const int e = l16 * 4 + k * 64;
      float4 wv = *(const float4*)(wrow + e);
      float4 hv = *(const float4*)(hsm + e);
      acc = fmaf(wv.x, hv.x, acc);
      acc = fmaf(wv.y, hv.y, acc);
      acc = fmaf(wv.z, hv.z, acc);
      acc = fmaf(wv.w, hv.w, acc);
    }
    acc += __shfl_xor(acc, 8);
    acc += __shfl_xor(acc, 4);
    acc += __shfl_xor(acc, 2);
    acc += __shfl_xor(acc, 1);
    if (l16 == 0) red[rl] = acc;
    __syncthreads();                 // B2: red ready; all hsm reads done
    if (tid < 4) {
      const int j = tid;
      float gi = xg0 + red[j];
      float gf = xg1 + red[4 + j];
      float gg = xg2 + red[8 + j];
      float go = xg3 + red[12 + j];
      float si = sigm_fast(gi);
      float sf = sigm_fast(gf);
      float tg = tanh_fast(gg);
      float so = sigm_fast(go);
      c_reg = fmaf(sf, c_reg, si * tg);
      float h = so * tanh_fast(c_reg);
      // publish FIRST (critical path): packet = (tag t+1, h bits)
      unsigned long long* dst = ((t + 1) & 1) ? pk1 : pk0;
      unsigned long long pk = ((unsigned long long)(unsigned)(t + 1) << 32)
                              | (unsigned long long)__float_as_uint(h);
      __hip_atomic_store(dst + u0 + j, pk, __ATOMIC_RELAXED, __HIP_MEMORY_SCOPE_AGENT);
      hsbf[(size_t)t * 1024 + u0 + j] = f2bf(h);
      if (t == 2047) { outHT[u0 + j] = h; outCT[u0 + j] = c_reg; }
      // prefetch next step's xW (completes under next poll)
      const int tn = (t < 2047) ? (t + 1) : 2047;
      const float* xr = xW + (size_t)tn * G4n + u0 + j;
      xg0 = xr[0]; xg1 = xr[1024]; xg2 = xr[2048]; xg3 = xr[3072];
    }
  }
}

// ---------------------------------------------------------------------------
// K3: logits = relu(hs_bf16 @ W_lin^T + b_lin) -> d_out [2048 x 32000] f32
// ---------------------------------------------------------------------------
__global__ __launch_bounds__(256) void gemm_logits(
    const unsigned short* __restrict__ hs, const float* __restrict__ Wlin,
    const float* __restrict__ blin, float* __restrict__ out)
{
  __shared__ unsigned short As[128][32];
  __shared__ unsigned short Bs[128][32];
  const int tid = threadIdx.x;
  const int n0 = blockIdx.x * 128;
  const int m0 = blockIdx.y * 128;
  const int r2 = tid >> 1, half = tid & 1;
  const int lane = tid & 63;
  const int wv = tid >> 6;
  const int wm = (wv >> 1) * 64;
  const int wn = (wv & 1) * 64;
  const int fr = lane & 15;
  const int fq = lane >> 4;
  f32x4 acc[4][4];
#pragma unroll
  for (int i = 0; i < 4; ++i)
#pragma unroll
    for (int j = 0; j < 4; ++j)
      acc[i][j] = (f32x4){0.f, 0.f, 0.f, 0.f};
  for (int kt = 0; kt < 32; ++kt) {
    const size_t ak = (size_t)(m0 + r2) * 1024 + kt * 32 + half * 16;
    int4 aA = *(const int4*)(hs + ak);
    int4 aB = *(const int4*)(hs + ak + 8);
    const size_t bk = (size_t)(n0 + r2) * 1024 + kt * 32 + half * 16;
    float4 b0 = *(const float4*)(Wlin + bk);
    float4 b1 = *(const float4*)(Wlin + bk + 4);
    float4 b2 = *(const float4*)(Wlin + bk + 8);
    float4 b3 = *(const float4*)(Wlin + bk + 12);
    __syncthreads();
    *(int4*)&As[r2][half * 16] = aA;
    *(int4*)&As[r2][half * 16 + 8] = aB;
    union { unsigned short u[8]; int4 v; } p0, p1;
    p0.u[0]=f2bf(b0.x); p0.u[1]=f2bf(b0.y); p0.u[2]=f2bf(b0.z); p0.u[3]=f2bf(b0.w);
    p0.u[4]=f2bf(b1.x); p0.u[5]=f2bf(b1.y); p0.u[6]=f2bf(b1.z); p0.u[7]=f2bf(b1.w);
    p1.u[0]=f2bf(b2.x); p1.u[1]=f2bf(b2.y); p1.u[2]=f2bf(b2.z); p1.u[3]=f2bf(b2.w);
    p1.u[4]=f2bf(b3.x); p1.u[5]=f2bf(b3.y); p1.u[6]=f2bf(b3.z); p1.u[7]=f2bf(b3.w);
    *(int4*)&Bs[r2][half * 16] = p0.v;
    *(int4*)&Bs[r2][half * 16 + 8] = p1.v;
    __syncthreads();
    short8 af[4], bfv[4];
#pragma unroll
    for (int i = 0; i < 4; ++i) af[i] = *(const short8*)&As[wm + i * 16 + fr][fq * 8];
#pragma unroll
    for (int j = 0; j < 4; ++j) bfv[j] = *(const short8*)&Bs[wn + j * 16 + fr][fq * 8];
#pragma unroll
    for (int i = 0; i < 4; ++i)
#pragma unroll
      for (int j = 0; j < 4; ++j)
        acc[i][j] = __builtin_amdgcn_mfma_f32_16x16x32_bf16(af[i], bfv[j], acc[i][j], 0, 0, 0);
  }
#pragma unroll
  for (int j = 0; j < 4; ++j) {
    const int col = n0 + wn + j * 16 + fr;
    const float bias = blin[col];
#pragma unroll
    for (int i = 0; i < 4; ++i) {
#pragma unroll
      for (int r = 0; r < 4; ++r) {
        const int row = m0 + wm + i * 16 + fq * 4 + r;
        float v = acc[i][j][r] + bias;
        out[(size_t)row * VOCABn + col] = fmaxf(v, 0.f);
      }
    }
  }
}

// ---------------------------------------------------------------------------
// K4: in-place log_softmax per row of d_out (2048 rows x 32000).
// ---------------------------------------------------------------------------
__global__ __launch_bounds__(256) void logsoftmax_rows(float* __restrict__ out)
{
  __shared__ float sred[4];
  __shared__ float ssum[4];
  const int tid = threadIdx.x;
  float* p = out + (size_t)blockIdx.x * VOCABn;
  float m = -1e30f;
  for (int i = tid; i < VOCABn / 4; i += 256) {
    float4 v = ((const float4*)p)[i];
    m = fmaxf(m, fmaxf(fmaxf(v.x, v.y), fmaxf(v.z, v.w)));
  }
#pragma unroll
  for (int s = 32; s >= 1; s >>= 1) m = fmaxf(m, __shfl_xor(m, s));
  if ((tid & 63) == 0) sred[tid >> 6] = m;
  __syncthreads();
  m = fmaxf(fmaxf(sred[0], sred[1]), fmaxf(sred[2], sred[3]));
  float s = 0.f;
  for (int i = tid; i < VOCABn / 4; i += 256) {
    float4 v = ((const float4*)p)[i];
    s += __expf(v.x - m) + __expf(v.y - m) + __expf(v.z - m) + __expf(v.w - m);
  }
#pragma unroll
  for (int sh = 32; sh >= 1; sh >>= 1) s += __shfl_xor(s, sh);
  if ((tid & 63) == 0) ssum[tid >> 6] = s;
  __syncthreads();
  s = ssum[0] + ssum[1] + ssum[2] + ssum[3];
  const float lse = m + logf(s);
  for (int i = tid; i < VOCABn / 4; i += 256) {
    float4 v = ((const float4*)p)[i];
    v.x -= lse; v.y -= lse; v.z -= lse; v.w -= lse;
    ((float4*)p)[i] = v;
  }
}

// ---------------------------------------------------------------------------
extern "C" void kernel_launch(void* const* d_in, const int* in_sizes, int n_in,
                              void* d_out, int out_size, void* d_ws, size_t ws_size,
                              hipStream_t stream) {
  const int*   input_x = (const int*)d_in[0];
  const float* emb     = (const float*)d_in[1];
  const float* Wih     = (const float*)d_in[2];
  const float* Whh     = (const float*)d_in[3];
  const float* bih     = (const float*)d_in[4];
  const float* bhh     = (const float*)d_in[5];
  const float* Wlin    = (const float*)d_in[6];
  const float* blin    = (const float*)d_in[7];
  float* out = (float*)d_out;
  char* ws = (char*)d_ws;

  unsigned long long* pk0 = (unsigned long long*)ws;            // 8KB
  unsigned long long* pk1 = (unsigned long long*)(ws + 8192);   // 8KB
  float* xW  = (float*)(ws + 131072);                           // 32MB
  unsigned short* hsbf = (unsigned short*)(ws + 131072 + (size_t)SEQn * G4n * 4); // 4MB
  float* outHT = out + (size_t)SEQn * VOCABn;
  float* outCT = outHT + 1024;

  hipMemsetAsync(d_ws, 0, 32768, stream);   // packets -> (h=0, tag=0)

  dim3 g1(64, 32);
  embed_xw<<<g1, 256, 0, stream>>>(input_x, emb, Wih, bih, bhh, xW);

  lstm_scan<<<256, 256, 70208, stream>>>(xW, Whh, pk0, pk1, hsbf, outHT, outCT);

  dim3 g2(250, 16);
  gemm_logits<<<g2, 256, 0, stream>>>(hsbf, Wlin, blin, out);

  logsoftmax_rows<<<2048, 256, 0, stream>>>(out);
}